// Round 8
// baseline (2194.089 us; speedup 1.0000x reference)
//
#include <hip/hip_runtime.h>
#include <stdint.h>

#define GAS __attribute__((address_space(1)))
#define LAS __attribute__((address_space(3)))

typedef __bf16 v8bf __attribute__((ext_vector_type(8)));
typedef float v4f __attribute__((ext_vector_type(4)));
typedef unsigned short u16;
typedef unsigned long long u64;

constexpr int kB = 256, kT = 128, kI = 512, kH = 1024, kO = 32;
constexpr int kBlocks = 1024, kThreads = 256;  // r8: 4 blocks/CU (16-row groups)
constexpr int KSX = kI / 32;   // 16 k-slices of 32 in x
constexpr int KSH = kH / 32;   // 32 k-slices of 32 in h
constexpr int QX = KSX / 4;    // 4  x-slices per wave (k-split)
constexpr int QH = KSH / 4;    // 8  h-slices per wave

// workspace layout (bytes) — EXACT r0 envelope (proven to fit; ws ~45-48 MB,
// rotation dead per r1/r2). Flags repacked: 16 groups x 64 producers x 8B
// stride = exactly the same 8 KB region.
constexpr size_t OFF_FLG = 0;
constexpr size_t OFF_H   = 8192;                                // 2 x 512KB frag-layout h
constexpr size_t SZ_H    = (size_t)2 * kB * kH * 2;
constexpr size_t OFF_XT  = OFF_H + SZ_H;                        // frag-tiled x (bf16)
constexpr size_t SZ_XT   = (size_t)kB * kT * kI * 2;            // 32 MB
constexpr size_t OFF_WIT = OFF_XT + SZ_XT;                      // 4 x 1MB wi frag tiles
constexpr size_t SZ_WIT  = (size_t)kH * kI * 2;
constexpr size_t OFF_WHT = OFF_WIT + 4 * SZ_WIT;                // 4 x 2MB wh frag tiles
constexpr size_t SZ_WHT  = (size_t)kH * kH * 2;

struct LstmParams {
  const u16* xt;        // frag-tiled x: [t][mt4][mi][ks(16)][lane][8]
  const u16* wit[4];    // frag-tiled wi: [ut][ks(16)][lane][8], gates i,f,g,o
  const u16* wht[4];    // frag-tiled wh: [ut][ks(32)][lane][8]
  const float* bi[4];
  const float* bh[4];
  const float* wfc;     // fp32 [O][H]
  float* out;           // fp32 [B][O]
  unsigned* flags;      // [16 groups][64 producers], 8B stride
  u16* hbuf;            // 2 x frag-layout h: [mt4][mi][ks(32)][lane][8]
};

static __device__ __forceinline__ float b2f(u16 v) {
  union { float f; uint32_t i; } u; u.i = ((uint32_t)v) << 16; return u.f;
}
static __device__ __forceinline__ u16 f2b(float f) {
  union { float f; uint32_t i; } u; u.f = f;
  return (u16)((u.i + 0x7fffu + ((u.i >> 16) & 1u)) >> 16);
}
static __device__ __forceinline__ float sigm(float x) { return 1.f / (1.f + __expf(-x)); }
static __device__ __forceinline__ float tanh_f(float x) {
  float e = __expf(2.f * x);
  return 1.f - 2.f / (e + 1.f);
}
// coherent async global->LDS, 16B/lane, sc0|sc1 (bypass L1/L2, LLC-serviced).
// PROVEN rules: (r7-orig) a vmcnt wait MUST sit between issue and any ds_read
// of the destination; (r4) phase H stays PER-WAVE private; (r7-pipe) publish
// flag++ IMMEDIATELY after the store drain — producer-side work before the
// publish lengthens the inter-block ring (cost ~2.5 us/step when violated).
static __device__ __forceinline__ void ld16c(const void* g, void* l) {
  __builtin_amdgcn_global_load_lds((const GAS uint32_t*)g, (LAS uint32_t*)l, 16, 0, 0x11);
}

// ---- prepass: fp32 -> bf16 frag-tiling (unchanged layouts) ------------------
__global__ __launch_bounds__(256) void cvt_x_tile(const float* __restrict__ x,
                                                  u16* __restrict__ xt) {
  const int gid = blockIdx.x * 256 + threadIdx.x;    // 2^21 threads exactly
  const int lane = gid & 63;
  const int ks = (gid >> 6) & 15;
  const int mi = (gid >> 10) & 3;
  const int mt = (gid >> 12) & 3;
  const int t  = gid >> 14;
  const int m = mt * 64 + mi * 16 + (lane & 15);
  const int k = ks * 32 + (lane >> 4) * 8;
  const float4* s = (const float4*)(x + ((size_t)m * kT + t) * kI + k);
  const float4 a = s[0], b = s[1];
  uint4 o = {f2b(a.x) | ((uint32_t)f2b(a.y) << 16), f2b(a.z) | ((uint32_t)f2b(a.w) << 16),
             f2b(b.x) | ((uint32_t)f2b(b.y) << 16), f2b(b.z) | ((uint32_t)f2b(b.w) << 16)};
  *(uint4*)(xt + (size_t)gid * 8) = o;
}

__global__ __launch_bounds__(256) void cvt_w_tile(const float* __restrict__ w,
                                                  u16* __restrict__ wt,
                                                  int K, int lgKS) {
  const int gid = blockIdx.x * 256 + threadIdx.x;
  const int lane = gid & 63;
  const int rest = gid >> 6;
  const int ks = rest & ((1 << lgKS) - 1);
  const int ut2 = rest >> lgKS;
  const int u = ut2 * 16 + (lane & 15);
  const int k = ks * 32 + (lane >> 4) * 8;
  const float4* s = (const float4*)(w + (size_t)u * K + k);
  const float4 a = s[0], b = s[1];
  uint4 o = {f2b(a.x) | ((uint32_t)f2b(a.y) << 16), f2b(a.z) | ((uint32_t)f2b(a.w) << 16),
             f2b(b.x) | ((uint32_t)f2b(b.y) << 16), f2b(b.z) | ((uint32_t)f2b(b.w) << 16)};
  *(uint4*)(wt + (size_t)gid * 8) = o;
}

// ---- persistent recurrence kernel ------------------------------------------
// r8 structure: r5 scaled to 4 blocks/CU. 1024 blocks x 256 threads.
// Block = (mt16, ut): mt16 = blk>>6 (16 groups of 16 batch rows = one mi
// sub-tile), ut = blk&63 (16 hidden units x 4 gates). Wave wv = K-quarter.
// Per block: staging 32 KB (8 KB/wave), Red 16 KB overlay, Hout 512B ->
// LDS 33.3 KB -> FOUR co-resident blocks per CU interleave latency phases
// (per-CU staging bytes unchanged vs r5: 4x32KB = 2x64KB).
__global__ __launch_bounds__(kThreads, 4) void lstm_kernel(LstmParams p) {
  // LDS map: [0,32K) per-wave 8 KB staging; Red (16 KB) overlaid on [0,16K)
  // — protected by the barrier after phase-H consume. [32K, 32K+512) Hout
  // [16 rows][16 units]. shFC (16 KB) overlaid at 0 post-loop.
  __shared__ __align__(16) char smem[33280];
  v4f* Red = (v4f*)smem;              // [slot = kq*4 + g][lane]
  float* Redf = (float*)smem;
  u16* Hout = (u16*)(smem + 32768);   // [16 rows][16 units]
  u16* shFC = (u16*)smem;             // 8 rows x 1024 bf16 (post-loop only)

  const int tid = threadIdx.x;
  const int lane = tid & 63;
  const int wv = tid >> 6;           // K-quarter owner
  const int blk = blockIdx.x;
  const int mt16 = blk >> 6;         // group 0..15 = 16 batch rows
  const int ut = blk & 63;           // unit column (16 units x 4 gates)
  const int mt4 = mt16 >> 2;         // frag-layout batch tile
  const int mi = mt16 & 3;           // mi sub-tile within mt4

  const int mloc = lane & 15;
  const int q = lane >> 4;
  const int uglob = ut * 16 + mloc;

  unsigned* gflags = p.flags + mt16 * 128;   // 64 slots, stride 2 u32 (8B)

  float bias[4];
#pragma unroll
  for (int g = 0; g < 4; ++g) bias[g] = p.bi[g][uglob] + p.bh[g][uglob];

  float creg = 0.f;   // cell state for row mt16*16 + wv*4 + q, unit uglob

  // ---- h-weights resident in registers (128 VGPRs); x-weights streamed ----
  v8bf bhh[QH][4];
#pragma unroll
  for (int g = 0; g < 4; ++g)
#pragma unroll
    for (int i = 0; i < QH; ++i)
      bhh[i][g] = *((const v8bf*)p.wht[g] + ((size_t)(ut * KSH + wv * QH + i) * 64 + lane));

  for (int t = 0; t < kT; ++t) {
    v4f acc[4];    // [gate] partials for this wave's K-quarter, 16-row tile
#pragma unroll
    for (int g = 0; g < 4; ++g) acc[g] = (v4f){0.f, 0.f, 0.f, 0.f};

    // ---- phase X: x-part MFMAs, pre-poll (independent of h); wi from L2 ----
    const v8bf* xf = (const v8bf*)p.xt + ((size_t)(t * 4 + mt4) * 4 * KSX) * 64;
#pragma unroll
    for (int i = 0; i < QX; ++i) {
      v8bf bxl[4];
#pragma unroll
      for (int g = 0; g < 4; ++g)
        bxl[g] = *((const v8bf*)p.wit[g] + ((size_t)(ut * KSX + wv * QX + i) * 64 + lane));
      const v8bf a = xf[(size_t)(mi * KSX + wv * QX + i) * 64 + lane];
#pragma unroll
      for (int g = 0; g < 4; ++g)
        acc[g] = __builtin_amdgcn_mfma_f32_16x16x32_bf16(a, bxl[g], acc[g], 0, 0, 0);
    }

    if (t > 0) {
      if (wv == 0) {   // centralized poll (r5-best): 64 lanes x 64 flags
        while (true) {
          unsigned v = __hip_atomic_load(&gflags[lane * 2], __ATOMIC_RELAXED,
                                         __HIP_MEMORY_SCOPE_AGENT);
          if (__ballot(v >= (unsigned)t) == ~0ull) break;
          __builtin_amdgcn_s_sleep(1);
        }
      }
      __syncthreads();   // release all waves; drains each wave's vmcnt so the
                         // counted waits below see exactly our 8 issues

      // ---- phase H: per-wave private staging (r4 lesson), counted-vmcnt
      // overlap (r3-proven): compute slices 0..3 while 4..7 stream.
      const char* hread = (const char*)(p.hbuf + (size_t)(t & 1) * kB * kH);
      char* myHs = smem + wv * 8192;

#pragma unroll
      for (int i = 0; i < QH; ++i) {
        const size_t sl = (size_t)((mt4 * 4 + mi) * KSH + wv * QH + i);
        ld16c(hread + sl * 1024 + lane * 16, myHs + i * 1024);
      }

      asm volatile("s_waitcnt vmcnt(4)" ::: "memory");
      __builtin_amdgcn_sched_barrier(0);
#pragma unroll
      for (int i = 0; i < 4; ++i) {
        const v8bf a = *(const v8bf*)(myHs + i * 1024 + lane * 16);
#pragma unroll
        for (int g = 0; g < 4; ++g)
          acc[g] = __builtin_amdgcn_mfma_f32_16x16x32_bf16(a, bhh[i][g], acc[g], 0, 0, 0);
      }
      asm volatile("s_waitcnt vmcnt(0)" ::: "memory");
      __builtin_amdgcn_sched_barrier(0);
#pragma unroll
      for (int i = 4; i < QH; ++i) {
        const v8bf a = *(const v8bf*)(myHs + i * 1024 + lane * 16);
#pragma unroll
        for (int g = 0; g < 4; ++g)
          acc[g] = __builtin_amdgcn_mfma_f32_16x16x32_bf16(a, bhh[i][g], acc[g], 0, 0, 0);
      }
    }

    __syncthreads();   // all phase-H ds_reads done: Red overlay now safe

    // ---- cross-wave K-reduction through LDS ----
#pragma unroll
    for (int g = 0; g < 4; ++g)
      Red[(wv * 4 + g) * 64 + lane] = acc[g];
    __syncthreads();

    // combine + gates: this thread owns row lrow = wv*4 + q, unit uglob.
    // C-frag element (row16, col): lane' = (row16>>2)*16 + col, reg = row16&3.
    {
      const int lrow = wv * 4 + q;
      const int lanep = (lrow >> 2) * 16 + mloc;
      const int reg = lrow & 3;
      float gacc[4];
#pragma unroll
      for (int g = 0; g < 4; ++g) {
        float s = 0.f;
#pragma unroll
        for (int kq = 0; kq < 4; ++kq)
          s += Redf[((kq * 4 + g) * 64 + lanep) * 4 + reg];
        gacc[g] = s;
      }
      const float iv = sigm(gacc[0] + bias[0]);
      const float fv = sigm(gacc[1] + bias[1]);
      const float gv = tanh_f(gacc[2] + bias[2]);
      const float ov = sigm(gacc[3] + bias[3]);
      creg = fv * creg + iv * gv;
      const float hv = ov * tanh_f(creg);
      Hout[lrow * 16 + mloc] = f2b(hv);
    }
    __syncthreads();   // Hout complete

    // coalesced write-through: this block's h = 2 contiguous 256B runs
    // (hbit 0..1); 64 threads x 8B.
    if (tid < 64) {
      u16* hw = p.hbuf + (size_t)((t + 1) & 1) * kB * kH;
      const int hbit = tid >> 5;
      const int idx = tid & 31;
      const int row16 = idx >> 1;
      const int j0 = (idx & 1) * 4;
      const int hi = (ut & 1) * 2 + hbit;
      const u64 v = *(const u64*)&Hout[row16 * 16 + hbit * 8 + j0];
      u64* dst = (u64*)((char*)hw +
                        ((size_t)((mt4 * 4 + mi) * KSH + (ut >> 1)) * 1024) +
                        hi * 256 + row16 * 16 + j0 * 2);
      __hip_atomic_store(dst, v, __ATOMIC_RELAXED, __HIP_MEMORY_SCOPE_AGENT);
    }

    __syncthreads();   // drains vmcnt: all h stores acked at LLC (r4-validated)
    if (tid == 0)      // publish IMMEDIATELY (r7 lesson)
      __hip_atomic_fetch_add(&gflags[ut * 2], 1u, __ATOMIC_RELAXED,
                             __HIP_MEMORY_SCOPE_AGENT);
  }

  // ---- FC + log_softmax: blocks 0..31, 8 rows x 32 cols. h_last in buf 0 ----
  if (blk < 32) {
    const int gg16 = blk >> 1;   // 16-row group of rows blk*8..+8
    if (wv == 0) {
      while (true) {
        unsigned v = __hip_atomic_load(&p.flags[gg16 * 128 + lane * 2], __ATOMIC_RELAXED,
                                       __HIP_MEMORY_SCOPE_AGENT);
        if (__ballot(v >= (unsigned)kT) == ~0ull) break;
        __builtin_amdgcn_s_sleep(1);
      }
    }
    __syncthreads();
    // stage 8 rows from frag-layout h into shFC[row][u] (small, once)
    {
      const int gg4 = blk >> 3;        // mt4 for frag indexing
      const int fmi = (blk >> 1) & 3;  // mi for frag indexing
      const int ks2 = tid >> 3;        // 0..31
      const int ug = (tid >> 1) & 3;   // unit 8-group
      const int rh = tid & 1;          // row half
      u64* hf = (u64*)p.hbuf;          // buffer 0 (kT even)
#pragma unroll
      for (int rr = 0; rr < 4; ++rr) {
        const int row_l = rh * 4 + rr;
        const int r16 = (blk & 1) * 8 + row_l;
        const int L = r16 | (ug << 4);
        const size_t fi = ((size_t)((gg4 * 4 + fmi) * KSH + ks2) * 64 + L) * 2;
        const u64 a = __hip_atomic_load(hf + fi, __ATOMIC_RELAXED, __HIP_MEMORY_SCOPE_AGENT);
        const u64 b = __hip_atomic_load(hf + fi + 1, __ATOMIC_RELAXED, __HIP_MEMORY_SCOPE_AGENT);
        u64* d = (u64*)&shFC[row_l * kH + ks2 * 32 + ug * 8];
        d[0] = a; d[1] = b;
      }
    }
    __syncthreads();
    const int row = tid >> 5;
    const int col = tid & 31;
    const u16* hr = &shFC[row * kH];
    const float* wr = p.wfc + (size_t)col * kH;
    float s = 0.f;
    for (int k = 0; k < kH; k += 4) {
      const float4 w4 = *(const float4*)(wr + k);
      s += b2f(hr[k]) * w4.x + b2f(hr[k + 1]) * w4.y +
           b2f(hr[k + 2]) * w4.z + b2f(hr[k + 3]) * w4.w;
    }
    float mx = s;
#pragma unroll
    for (int off = 16; off; off >>= 1) mx = fmaxf(mx, __shfl_xor(mx, off, 32));
    const float ex = __expf(s - mx);
    float se = ex;
#pragma unroll
    for (int off = 16; off; off >>= 1) se += __shfl_xor(se, off, 32);
    p.out[(blk * 8 + row) * kO + col] = s - mx - __logf(se);
  }
}

extern "C" void kernel_launch(void* const* d_in, const int* in_sizes, int n_in,
                              void* d_out, int out_size, void* d_ws, size_t ws_size,
                              hipStream_t stream) {
  (void)in_sizes; (void)n_in; (void)out_size; (void)ws_size;
  char* ws = (char*)d_ws;

  u16* xt = (u16*)(ws + OFF_XT);
  u16 *wit[4], *wht[4];
  for (int g = 0; g < 4; ++g) {
    wit[g] = (u16*)(ws + OFF_WIT + (size_t)g * SZ_WIT);
    wht[g] = (u16*)(ws + OFF_WHT + (size_t)g * SZ_WHT);
  }

  // dict order: x, (w_ii,w_hi,b_ii,b_hi), (w_if,w_hf,b_if,b_hf),
  //             (w_io,w_ho,b_io,b_ho), (w_ic,w_hc,b_ic,b_hc), w_fc
  // gate order: 0=i, 1=f, 2=g(candidate), 3=o
  const int gsrc[4] = {1, 5, 13, 9};

  hipMemsetAsync(d_ws, 0, 8192, stream);   // zero barrier flags (16 groups x 64 x 8B)

  cvt_x_tile<<<8192, 256, 0, stream>>>((const float*)d_in[0], xt);
  for (int g = 0; g < 4; ++g) {
    cvt_w_tile<<<256, 256, 0, stream>>>((const float*)d_in[gsrc[g]], wit[g], kI, 4);
    cvt_w_tile<<<512, 256, 0, stream>>>((const float*)d_in[gsrc[g] + 1], wht[g], kH, 5);
  }

  LstmParams p;
  p.xt = xt;
  for (int g = 0; g < 4; ++g) {
    p.wit[g] = wit[g];
    p.wht[g] = wht[g];
    p.bi[g] = (const float*)d_in[gsrc[g] + 2];
    p.bh[g] = (const float*)d_in[gsrc[g] + 3];
  }
  p.wfc = (const float*)d_in[17];
  p.out = (float*)d_out;
  p.flags = (unsigned*)(ws + OFF_FLG);
  p.hbuf = (u16*)(ws + OFF_H);

  void* args[] = {&p};
  hipError_t e = hipLaunchCooperativeKernel((void*)lstm_kernel, dim3(kBlocks),
                                            dim3(kThreads), args, 0, stream);
  if (e != hipSuccess) {
    // Never fail silently (r5 lesson). __launch_bounds__(256,4) + 33.3 KB LDS
    // guarantee 4 blocks/CU -> all 1024 blocks co-resident on 256 CUs, so a
    // plain launch co-schedules everything safely.
    (void)hipGetLastError();   // clear sticky error
    lstm_kernel<<<dim3(kBlocks), dim3(kThreads), 0, stream>>>(p);
  }
}

// Round 9
// 1228.299 us; speedup vs baseline: 1.7863x; 1.7863x over previous
//
#include <hip/hip_runtime.h>
#include <stdint.h>

#define GAS __attribute__((address_space(1)))
#define LAS __attribute__((address_space(3)))

typedef __bf16 v8bf __attribute__((ext_vector_type(8)));
typedef float v4f __attribute__((ext_vector_type(4)));
typedef unsigned short u16;
typedef unsigned long long u64;

constexpr int kB = 256, kT = 128, kI = 512, kH = 1024, kO = 32;
constexpr int kBlocks = 512, kThreads = 256;   // r5: 2 blocks/CU (32-row groups)
constexpr int KSX = kI / 32;   // 16 k-slices of 32 in x
constexpr int KSH = kH / 32;   // 32 k-slices of 32 in h
constexpr int QX = KSX / 4;    // 4  x-slices per wave (k-split)
constexpr int QH = KSH / 4;    // 8  h-slices per wave

// workspace layout (bytes) — EXACT r0 layout (ws ~45 MB: rotation dead, r1/r2)
constexpr size_t OFF_FLG = 0;                                   // flags[8][64], 16B stride = 8 KB
constexpr size_t OFF_H   = 8192;                                // 2 x 512KB frag-layout h
constexpr size_t SZ_H    = (size_t)2 * kB * kH * 2;
constexpr size_t OFF_XT  = OFF_H + SZ_H;                        // frag-tiled x (bf16)
constexpr size_t SZ_XT   = (size_t)kB * kT * kI * 2;            // 32 MB
constexpr size_t OFF_WIT = OFF_XT + SZ_XT;                      // 4 x 1MB wi frag tiles
constexpr size_t SZ_WIT  = (size_t)kH * kI * 2;
constexpr size_t OFF_WHT = OFF_WIT + 4 * SZ_WIT;                // 4 x 2MB wh frag tiles
constexpr size_t SZ_WHT  = (size_t)kH * kH * 2;

struct LstmParams {
  const u16* xt;        // frag-tiled x: [t][mt4][mi][ks(16)][lane][8]
  const u16* wit[4];    // frag-tiled wi: [ut][ks(16)][lane][8], gates i,f,g,o
  const u16* wht[4];    // frag-tiled wh: [ut][ks(32)][lane][8]
  const float* bi[4];
  const float* bh[4];
  const float* wfc;     // fp32 [O][H]
  float* out;           // fp32 [B][O]
  unsigned* flags;      // [8 groups][64 producers], 16B stride (PRIVATE lines)
  u16* hbuf;            // 2 x frag-layout h: [mt4][mi][ks(32)][lane][8]
};

static __device__ __forceinline__ float b2f(u16 v) {
  union { float f; uint32_t i; } u; u.i = ((uint32_t)v) << 16; return u.f;
}
static __device__ __forceinline__ u16 f2b(float f) {
  union { float f; uint32_t i; } u; u.f = f;
  return (u16)((u.i + 0x7fffu + ((u.i >> 16) & 1u)) >> 16);
}
static __device__ __forceinline__ float sigm(float x) { return 1.f / (1.f + __expf(-x)); }
static __device__ __forceinline__ float tanh_f(float x) {
  float e = __expf(2.f * x);
  return 1.f - 2.f / (e + 1.f);
}
// coherent async global->LDS, 16B/lane, sc0|sc1 (bypass L1/L2, LLC-serviced).
// PROVEN rules: (r7-orig) a vmcnt wait MUST sit between issue and any ds_read
// of the destination; (r4) phase H stays PER-WAVE private; (r7) publish
// flag++ IMMEDIATELY after the store drain; (r8) >=4 waves/EU spills the
// register-resident h-weights (VGPR cap 128) -> 2 blocks/CU is the ceiling.
static __device__ __forceinline__ void ld16c(const void* g, void* l) {
  __builtin_amdgcn_global_load_lds((const GAS uint32_t*)g, (LAS uint32_t*)l, 16, 0, 0x11);
}

// ---- prepass: fp32 -> bf16 frag-tiling (unchanged layouts) ------------------
__global__ __launch_bounds__(256) void cvt_x_tile(const float* __restrict__ x,
                                                  u16* __restrict__ xt) {
  const int gid = blockIdx.x * 256 + threadIdx.x;    // 2^21 threads exactly
  const int lane = gid & 63;
  const int ks = (gid >> 6) & 15;
  const int mi = (gid >> 10) & 3;
  const int mt = (gid >> 12) & 3;
  const int t  = gid >> 14;
  const int m = mt * 64 + mi * 16 + (lane & 15);
  const int k = ks * 32 + (lane >> 4) * 8;
  const float4* s = (const float4*)(x + ((size_t)m * kT + t) * kI + k);
  const float4 a = s[0], b = s[1];
  uint4 o = {f2b(a.x) | ((uint32_t)f2b(a.y) << 16), f2b(a.z) | ((uint32_t)f2b(a.w) << 16),
             f2b(b.x) | ((uint32_t)f2b(b.y) << 16), f2b(b.z) | ((uint32_t)f2b(b.w) << 16)};
  *(uint4*)(xt + (size_t)gid * 8) = o;
}

__global__ __launch_bounds__(256) void cvt_w_tile(const float* __restrict__ w,
                                                  u16* __restrict__ wt,
                                                  int K, int lgKS) {
  const int gid = blockIdx.x * 256 + threadIdx.x;
  const int lane = gid & 63;
  const int rest = gid >> 6;
  const int ks = rest & ((1 << lgKS) - 1);
  const int ut2 = rest >> lgKS;
  const int u = ut2 * 16 + (lane & 15);
  const int k = ks * 32 + (lane >> 4) * 8;
  const float4* s = (const float4*)(w + (size_t)u * K + k);
  const float4 a = s[0], b = s[1];
  uint4 o = {f2b(a.x) | ((uint32_t)f2b(a.y) << 16), f2b(a.z) | ((uint32_t)f2b(a.w) << 16),
             f2b(b.x) | ((uint32_t)f2b(b.y) << 16), f2b(b.z) | ((uint32_t)f2b(b.w) << 16)};
  *(uint4*)(wt + (size_t)gid * 8) = o;
}

// ---- persistent recurrence kernel ------------------------------------------
// r9 structure: r5 (512 blocks x 256 thr, 2 blocks/CU, centralized poll,
// immediate publish) + ANTI-PHASE STAGGER. Co-resident pair is (b, b+256) =
// groups g and g+4 under round-robin dispatch; both rings have identical
// natural periods and start together, so they phase-lock and the CU idles
// during both blocks' poll/stage waits (MfmaUtil+VALU = 31% vs ~65%
// achievable). Delaying groups 4-7 once by ~half a period (~8k clocks) puts
// each CU's two rings in anti-phase; groups are fully independent (flags and
// h-slices group-private), so a uniform group shift is timing-safe.
__global__ __launch_bounds__(kThreads, 2) void lstm_kernel(LstmParams p) {
  // LDS map: [0,64K) per-wave 16 KB staging; Red (32 KB) overlaid on [0,32K)
  // — protected by the barrier after phase-H consume. [64K,65K) Hout
  // [32 rows][16 units]. shFC (16 KB) overlaid at 0 post-loop.
  __shared__ __align__(16) char smem[66560];
  v4f* Red = (v4f*)smem;              // [slot = kq*8 + ml*4 + g][lane]
  float* Redf = (float*)smem;
  u16* Hout = (u16*)(smem + 65536);   // [32 rows][16 units]
  u16* shFC = (u16*)smem;             // 8 rows x 1024 bf16 (post-loop only)

  const int tid = threadIdx.x;
  const int lane = tid & 63;
  const int wv = tid >> 6;           // K-quarter owner
  const int blk = blockIdx.x;
  const int mt8 = blk >> 6;          // group 0..7 = 32 batch rows
  const int ut = blk & 63;           // unit column (16 units x 4 gates)
  const int mt4 = mt8 >> 1;          // frag-layout batch tile
  const int mib = (mt8 & 1) * 2;     // mi base within mt4 (2 sub-tiles)

  const int mloc = lane & 15;
  const int q = lane >> 4;
  const int uglob = ut * 16 + mloc;

  unsigned* gflags = p.flags + mt8 * 256;   // 64 slots, stride 4 u32 (16B)

  float bias[4];
#pragma unroll
  for (int g = 0; g < 4; ++g) bias[g] = p.bi[g][uglob] + p.bh[g][uglob];

  float creg[2] = {0.f, 0.f};   // cell state for rows mt8*32 + wv*8 + q*2 + r

  // ---- h-weights resident in registers (128 VGPRs); x-weights streamed ----
  v8bf bhh[QH][4];
#pragma unroll
  for (int g = 0; g < 4; ++g)
#pragma unroll
    for (int i = 0; i < QH; ++i)
      bhh[i][g] = *((const v8bf*)p.wht[g] + ((size_t)(ut * KSH + wv * QH + i) * 64 + lane));

  // ---- r9 anti-phase stagger: shift groups 4-7 by ~half a step period so
  // each CU's co-resident pair (groups g, g+4) interleaves compute with the
  // partner's poll/stage wait. One-shot cost ~4 us; gain every step.
  if (mt8 >= 4)
    __builtin_amdgcn_s_sleep(127);   // ~64*127 ≈ 8k clocks ≈ half of 8.3 us

  for (int t = 0; t < kT; ++t) {
    v4f acc[2][4];    // [mi_loc][gate] partials for this wave's K-quarter
#pragma unroll
    for (int m = 0; m < 2; ++m)
#pragma unroll
      for (int g = 0; g < 4; ++g) acc[m][g] = (v4f){0.f, 0.f, 0.f, 0.f};

    // ---- phase X: x-part MFMAs, pre-poll (independent of h); wi from L2 ----
    const v8bf* xf = (const v8bf*)p.xt + ((size_t)(t * 4 + mt4) * 4 * KSX) * 64;
#pragma unroll
    for (int i = 0; i < QX; ++i) {
      v8bf bxl[4];
#pragma unroll
      for (int g = 0; g < 4; ++g)
        bxl[g] = *((const v8bf*)p.wit[g] + ((size_t)(ut * KSX + wv * QX + i) * 64 + lane));
#pragma unroll
      for (int ml = 0; ml < 2; ++ml) {
        const v8bf a = xf[(size_t)((mib + ml) * KSX + wv * QX + i) * 64 + lane];
#pragma unroll
        for (int g = 0; g < 4; ++g)
          acc[ml][g] = __builtin_amdgcn_mfma_f32_16x16x32_bf16(a, bxl[g], acc[ml][g], 0, 0, 0);
      }
    }

    if (t > 0) {
      if (wv == 0) {   // centralized poll (r5-best): 64 lanes x 64 flags
        while (true) {
          unsigned v = __hip_atomic_load(&gflags[lane * 4], __ATOMIC_RELAXED,
                                         __HIP_MEMORY_SCOPE_AGENT);
          if (__ballot(v >= (unsigned)t) == ~0ull) break;
          __builtin_amdgcn_s_sleep(1);
        }
      }
      __syncthreads();   // release all waves; also drains each wave's vmcnt
                         // so the counted waits below see exactly our issues

      // ---- phase H: per-wave private staging (r4 lesson), counted-vmcnt
      // overlap (r3-proven): compute mi0 while mi1 streams.
      const char* hread = (const char*)(p.hbuf + (size_t)(t & 1) * kB * kH);
      char* myHs = smem + wv * 16384;

#define STAGE_ML(ML)                                                          \
  _Pragma("unroll")                                                           \
  for (int i = 0; i < QH; ++i) {                                              \
    const size_t sl = (size_t)((mt4 * 4 + mib + (ML)) * KSH + wv * QH + i);   \
    ld16c(hread + sl * 1024 + lane * 16, myHs + ((ML) * QH + i) * 1024);      \
  }
#define COMPUTE_ML(ML)                                                        \
  _Pragma("unroll")                                                           \
  for (int i = 0; i < QH; ++i) {                                              \
    const v8bf a = *(const v8bf*)(myHs + ((ML) * QH + i) * 1024 + lane * 16); \
    _Pragma("unroll")                                                         \
    for (int g = 0; g < 4; ++g)                                               \
      acc[(ML)][g] = __builtin_amdgcn_mfma_f32_16x16x32_bf16(                 \
          a, bhh[i][g], acc[(ML)][g], 0, 0, 0);                               \
  }

      STAGE_ML(0) STAGE_ML(1)
      asm volatile("s_waitcnt vmcnt(8)" ::: "memory");
      __builtin_amdgcn_sched_barrier(0);
      COMPUTE_ML(0)
      asm volatile("s_waitcnt vmcnt(0)" ::: "memory");
      __builtin_amdgcn_sched_barrier(0);
      COMPUTE_ML(1)
#undef STAGE_ML
#undef COMPUTE_ML
    }

    __syncthreads();   // all phase-H ds_reads done: Red overlay now safe

    // ---- cross-wave K-reduction through LDS ----
#pragma unroll
    for (int ml = 0; ml < 2; ++ml)
#pragma unroll
      for (int g = 0; g < 4; ++g)
        Red[(wv * 8 + ml * 4 + g) * 64 + lane] = acc[ml][g];
    __syncthreads();

    // combine + gates: this thread owns rows mt8*32 + wv*8 + q*2 + {0,1},
    // unit uglob. C-frag element: row16 = q'*4 + reg, col = lane&15.
#pragma unroll
    for (int r = 0; r < 2; ++r) {
      const int lrow = wv * 8 + q * 2 + r;
      const int ml = lrow >> 4;
      const int r16 = lrow & 15;
      const int qp = r16 >> 2;
      const int reg = r16 & 3;
      float gacc[4];
#pragma unroll
      for (int g = 0; g < 4; ++g) {
        float s = 0.f;
#pragma unroll
        for (int kq = 0; kq < 4; ++kq)
          s += Redf[((kq * 8 + ml * 4 + g) * 64 + qp * 16 + mloc) * 4 + reg];
        gacc[g] = s;
      }
      const float iv = sigm(gacc[0] + bias[0]);
      const float fv = sigm(gacc[1] + bias[1]);
      const float gv = tanh_f(gacc[2] + bias[2]);
      const float ov = sigm(gacc[3] + bias[3]);
      creg[r] = fv * creg[r] + iv * gv;
      const float hv = ov * tanh_f(creg[r]);
      Hout[lrow * 16 + mloc] = f2b(hv);
    }
    __syncthreads();   // Hout complete

    // coalesced write-through: this block's h = 4 contiguous 256B runs
    // (mi_loc 0..1) x (hbit 0..1); 128 threads x 8B.
    if (tid < 128) {
      u16* hw = p.hbuf + (size_t)((t + 1) & 1) * kB * kH;
      const int run = tid >> 5;        // 0..3
      const int ml = run >> 1;
      const int hbit = run & 1;
      const int idx = tid & 31;
      const int row16 = idx >> 1;
      const int j0 = (idx & 1) * 4;
      const int hi = (ut & 1) * 2 + hbit;
      const u64 v = *(const u64*)&Hout[(ml * 16 + row16) * 16 + hbit * 8 + j0];
      u64* dst = (u64*)((char*)hw +
                        ((size_t)((mt4 * 4 + mib + ml) * KSH + (ut >> 1)) * 1024) +
                        hi * 256 + row16 * 16 + j0 * 2);
      __hip_atomic_store(dst, v, __ATOMIC_RELAXED, __HIP_MEMORY_SCOPE_AGENT);
    }

    __syncthreads();   // drains vmcnt: all h stores acked at LLC (r4-validated)
    if (tid == 0)      // publish IMMEDIATELY (r7 lesson)
      __hip_atomic_fetch_add(&gflags[ut * 4], 1u, __ATOMIC_RELAXED,
                             __HIP_MEMORY_SCOPE_AGENT);
  }

  // ---- FC + log_softmax: blocks 0..31, 8 rows x 32 cols. h_last in buf 0 ----
  if (blk < 32) {
    const int gg8 = blk >> 2;   // mt8 group of rows blk*8..+8
    if (wv == 0) {   // FC needs the WHOLE h -> centralized 64-flag poll (once)
      while (true) {
        unsigned v = __hip_atomic_load(&p.flags[gg8 * 256 + lane * 4], __ATOMIC_RELAXED,
                                       __HIP_MEMORY_SCOPE_AGENT);
        if (__ballot(v >= (unsigned)kT) == ~0ull) break;
        __builtin_amdgcn_s_sleep(1);
      }
    }
    __syncthreads();
    // stage 8 rows from frag-layout h into shFC[row][u] (small, once)
    {
      const int gg4 = blk >> 3;        // mt4 for frag indexing
      const int mi = (blk >> 1) & 3;
      const int ks2 = tid >> 3;        // 0..31
      const int ug = (tid >> 1) & 3;   // unit 8-group
      const int rh = tid & 1;          // row half
      u64* hf = (u64*)p.hbuf;          // buffer 0 (kT even)
#pragma unroll
      for (int rr = 0; rr < 4; ++rr) {
        const int row_l = rh * 4 + rr;
        const int r16 = (blk & 1) * 8 + row_l;
        const int L = r16 | (ug << 4);
        const size_t fi = ((size_t)((gg4 * 4 + mi) * KSH + ks2) * 64 + L) * 2;
        const u64 a = __hip_atomic_load(hf + fi, __ATOMIC_RELAXED, __HIP_MEMORY_SCOPE_AGENT);
        const u64 b = __hip_atomic_load(hf + fi + 1, __ATOMIC_RELAXED, __HIP_MEMORY_SCOPE_AGENT);
        u64* d = (u64*)&shFC[row_l * kH + ks2 * 32 + ug * 8];
        d[0] = a; d[1] = b;
      }
    }
    __syncthreads();
    const int row = tid >> 5;
    const int col = tid & 31;
    const u16* hr = &shFC[row * kH];
    const float* wr = p.wfc + (size_t)col * kH;
    float s = 0.f;
    for (int k = 0; k < kH; k += 4) {
      const float4 w4 = *(const float4*)(wr + k);
      s += b2f(hr[k]) * w4.x + b2f(hr[k + 1]) * w4.y +
           b2f(hr[k + 2]) * w4.z + b2f(hr[k + 3]) * w4.w;
    }
    float mx = s;
#pragma unroll
    for (int off = 16; off; off >>= 1) mx = fmaxf(mx, __shfl_xor(mx, off, 32));
    const float ex = __expf(s - mx);
    float se = ex;
#pragma unroll
    for (int off = 16; off; off >>= 1) se += __shfl_xor(se, off, 32);
    p.out[(blk * 8 + row) * kO + col] = s - mx - __logf(se);
  }
}

extern "C" void kernel_launch(void* const* d_in, const int* in_sizes, int n_in,
                              void* d_out, int out_size, void* d_ws, size_t ws_size,
                              hipStream_t stream) {
  (void)in_sizes; (void)n_in; (void)out_size; (void)ws_size;
  char* ws = (char*)d_ws;

  u16* xt = (u16*)(ws + OFF_XT);
  u16 *wit[4], *wht[4];
  for (int g = 0; g < 4; ++g) {
    wit[g] = (u16*)(ws + OFF_WIT + (size_t)g * SZ_WIT);
    wht[g] = (u16*)(ws + OFF_WHT + (size_t)g * SZ_WHT);
  }

  // dict order: x, (w_ii,w_hi,b_ii,b_hi), (w_if,w_hf,b_if,b_hf),
  //             (w_io,w_ho,b_io,b_ho), (w_ic,w_hc,b_ic,b_hc), w_fc
  // gate order: 0=i, 1=f, 2=g(candidate), 3=o
  const int gsrc[4] = {1, 5, 13, 9};

  hipMemsetAsync(d_ws, 0, 8192, stream);   // zero barrier flags (8 groups x 64)

  cvt_x_tile<<<8192, 256, 0, stream>>>((const float*)d_in[0], xt);
  for (int g = 0; g < 4; ++g) {
    cvt_w_tile<<<256, 256, 0, stream>>>((const float*)d_in[gsrc[g]], wit[g], kI, 4);
    cvt_w_tile<<<512, 256, 0, stream>>>((const float*)d_in[gsrc[g] + 1], wht[g], kH, 5);
  }

  LstmParams p;
  p.xt = xt;
  for (int g = 0; g < 4; ++g) {
    p.wit[g] = wit[g];
    p.wht[g] = wht[g];
    p.bi[g] = (const float*)d_in[gsrc[g] + 2];
    p.bh[g] = (const float*)d_in[gsrc[g] + 3];
  }
  p.wfc = (const float*)d_in[17];
  p.out = (float*)d_out;
  p.flags = (unsigned*)(ws + OFF_FLG);
  p.hbuf = (u16*)(ws + OFF_H);

  void* args[] = {&p};
  hipError_t e = hipLaunchCooperativeKernel((void*)lstm_kernel, dim3(kBlocks),
                                            dim3(kThreads), args, 0, stream);
  if (e != hipSuccess) {
    // Never fail silently (r5 lesson). __launch_bounds__(256,2) + 66.5 KB LDS
    // guarantee 2 blocks/CU -> all 512 blocks co-resident on 256 CUs; the
    // group-contiguous mapping additionally makes partial residency safe.
    (void)hipGetLastError();   // clear sticky error
    lstm_kernel<<<dim3(kBlocks), dim3(kThreads), 0, stream>>>(p);
  }
}

// Round 10
// 1191.856 us; speedup vs baseline: 1.8409x; 1.0306x over previous
//
#include <hip/hip_runtime.h>
#include <stdint.h>

#define GAS __attribute__((address_space(1)))
#define LAS __attribute__((address_space(3)))

typedef __bf16 v8bf __attribute__((ext_vector_type(8)));
typedef float v4f __attribute__((ext_vector_type(4)));
typedef unsigned short u16;
typedef unsigned long long u64;

constexpr int kB = 256, kT = 128, kI = 512, kH = 1024, kO = 32;
constexpr int kBlocks = 512, kThreads = 256;   // r5: 2 blocks/CU (32-row groups)
constexpr int KSX = kI / 32;   // 16 k-slices of 32 in x
constexpr int KSH = kH / 32;   // 32 k-slices of 32 in h
constexpr int QX = KSX / 4;    // 4  x-slices per wave (k-split)
constexpr int QH = KSH / 4;    // 8  h-slices per wave

// workspace layout (bytes) — EXACT r0 layout (ws ~45 MB: rotation dead, r1/r2)
constexpr size_t OFF_FLG = 0;                                   // flags[8][64], 16B stride = 8 KB
constexpr size_t OFF_H   = 8192;                                // 2 x 512KB frag-layout h
constexpr size_t SZ_H    = (size_t)2 * kB * kH * 2;
constexpr size_t OFF_XT  = OFF_H + SZ_H;                        // frag-tiled x (bf16)
constexpr size_t SZ_XT   = (size_t)kB * kT * kI * 2;            // 32 MB
constexpr size_t OFF_WIT = OFF_XT + SZ_XT;                      // 4 x 1MB wi frag tiles
constexpr size_t SZ_WIT  = (size_t)kH * kI * 2;
constexpr size_t OFF_WHT = OFF_WIT + 4 * SZ_WIT;                // 4 x 2MB wh frag tiles
constexpr size_t SZ_WHT  = (size_t)kH * kH * 2;

struct LstmParams {
  const u16* xt;        // frag-tiled x: [t][mt4][mi][ks(16)][lane][8]
  const u16* wit[4];    // frag-tiled wi: [ut][ks(16)][lane][8], gates i,f,g,o
  const u16* wht[4];    // frag-tiled wh: [ut][ks(32)][lane][8]
  const float* bi[4];
  const float* bh[4];
  const float* wfc;     // fp32 [O][H]
  float* out;           // fp32 [B][O]
  unsigned* flags;      // [8 groups][64 producers], 16B stride (PRIVATE lines)
  u16* hbuf;            // 2 x frag-layout h: [mt4][mi][ks(32)][lane][8]
};

struct PrepassParams {
  const float* x;
  const float* wi[4];
  const float* wh[4];
  u16* xt;
  u16* wit[4];
  u16* wht[4];
  unsigned* flags;
};

static __device__ __forceinline__ float b2f(u16 v) {
  union { float f; uint32_t i; } u; u.i = ((uint32_t)v) << 16; return u.f;
}
static __device__ __forceinline__ u16 f2b(float f) {
  union { float f; uint32_t i; } u; u.f = f;
  return (u16)((u.i + 0x7fffu + ((u.i >> 16) & 1u)) >> 16);
}
static __device__ __forceinline__ float sigm(float x) { return 1.f / (1.f + __expf(-x)); }
static __device__ __forceinline__ float tanh_f(float x) {
  float e = __expf(2.f * x);
  return 1.f - 2.f / (e + 1.f);
}
// coherent async global->LDS, 16B/lane, sc0|sc1 (bypass L1/L2, LLC-serviced).
// PROVEN rules: (r7-orig) a vmcnt wait MUST sit between issue and any ds_read
// of the destination; (r4) phase H stays PER-WAVE private; (r7) publish
// flag++ IMMEDIATELY after the store drain; (r8) >=4 waves/EU spills the
// register-resident h-weights (VGPR cap 128) -> 2 blocks/CU is the ceiling;
// (r9) anti-phase stagger is a null — the limiter is the shared coherent-read
// path (~3.9 TB/s at 32 MB/step), not CU-local phase-locking.
static __device__ __forceinline__ void ld16c(const void* g, void* l) {
  __builtin_amdgcn_global_load_lds((const GAS uint32_t*)g, (LAS uint32_t*)l, 16, 0, 0x11);
}

// ---- fused prepass: fp32 -> bf16 frag-tiling + flag zeroing (ONE launch) ----
// r10: the 10-dispatch prepass tail (memset + cvt_x + 8 cvt_w) was ~140 us of
// mostly launch/dispatch overhead on a serialized stream; the actual copy work
// is ~25-30 us of HBM traffic. Fuse everything into one grid, branch on
// blockIdx (wave-uniform): [0,8192) x-tiles, [8192,9216) wi, [9216,11264) wh,
// block 11264 zeros flags. Stream order still guarantees prepass completes
// before lstm_kernel launches.
static __device__ __forceinline__ void cvt_w_body(const float* __restrict__ w,
                                                  u16* __restrict__ wt,
                                                  int K, int lgKS, int gid) {
  const int lane = gid & 63;
  const int rest = gid >> 6;
  const int ks = rest & ((1 << lgKS) - 1);
  const int ut2 = rest >> lgKS;
  const int u = ut2 * 16 + (lane & 15);
  const int k = ks * 32 + (lane >> 4) * 8;
  const float4* s = (const float4*)(w + (size_t)u * K + k);
  const float4 a = s[0], b = s[1];
  uint4 o = {f2b(a.x) | ((uint32_t)f2b(a.y) << 16), f2b(a.z) | ((uint32_t)f2b(a.w) << 16),
             f2b(b.x) | ((uint32_t)f2b(b.y) << 16), f2b(b.z) | ((uint32_t)f2b(b.w) << 16)};
  *(uint4*)(wt + (size_t)gid * 8) = o;
}

__global__ __launch_bounds__(256) void prepass(PrepassParams pp) {
  const int blk = blockIdx.x;
  const int tid = threadIdx.x;
  if (blk < 8192) {
    // x[m][t][k] -> xt frag order [t][mt][mi][ks][lane][8]
    const int gid = blk * 256 + tid;    // 2^21 threads exactly
    const int lane = gid & 63;
    const int ks = (gid >> 6) & 15;
    const int mi = (gid >> 10) & 3;
    const int mt = (gid >> 12) & 3;
    const int t  = gid >> 14;
    const int m = mt * 64 + mi * 16 + (lane & 15);
    const int k = ks * 32 + (lane >> 4) * 8;
    const float4* s = (const float4*)(pp.x + ((size_t)m * kT + t) * kI + k);
    const float4 a = s[0], b = s[1];
    uint4 o = {f2b(a.x) | ((uint32_t)f2b(a.y) << 16), f2b(a.z) | ((uint32_t)f2b(a.w) << 16),
               f2b(b.x) | ((uint32_t)f2b(b.y) << 16), f2b(b.z) | ((uint32_t)f2b(b.w) << 16)};
    *(uint4*)(pp.xt + (size_t)gid * 8) = o;
  } else if (blk < 8192 + 4 * 256) {
    const int r = blk - 8192;
    const int g = r >> 8;               // gate
    const int gid = (r & 255) * 256 + tid;
    cvt_w_body(pp.wi[g], pp.wit[g], kI, 4, gid);
  } else if (blk < 8192 + 4 * 256 + 4 * 512) {
    const int r = blk - (8192 + 4 * 256);
    const int g = r >> 9;               // gate
    const int gid = (r & 511) * 256 + tid;
    cvt_w_body(pp.wh[g], pp.wht[g], kH, 5, gid);
  } else {
    // zero the 8 KB flag region: 256 threads x 4 u64
    u64* f = (u64*)pp.flags;
#pragma unroll
    for (int i = 0; i < 4; ++i) f[tid * 4 + i] = 0ull;
  }
}

// ---- persistent recurrence kernel ------------------------------------------
// r5 structure (best measured: 1066 us): 512 blocks x 256 threads, 2 blocks/
// CU. Block = (mt8, ut): mt8 = blk>>6 (8 groups of 32 batch rows, GROUP-
// CONTIGUOUS for fallback safety), ut = blk&63 (16 hidden units x 4 gates).
// Wave wv = K-quarter owner. Per block: 2 mi sub-tiles, staging 64 KB, Red
// 32 KB overlay -> LDS 66.5 KB -> two co-resident blocks/CU interleave.
__global__ __launch_bounds__(kThreads, 2) void lstm_kernel(LstmParams p) {
  // LDS map: [0,64K) per-wave 16 KB staging; Red (32 KB) overlaid on [0,32K)
  // — protected by the barrier after phase-H consume. [64K,65K) Hout
  // [32 rows][16 units]. shFC (16 KB) overlaid at 0 post-loop.
  __shared__ __align__(16) char smem[66560];
  v4f* Red = (v4f*)smem;              // [slot = kq*8 + ml*4 + g][lane]
  float* Redf = (float*)smem;
  u16* Hout = (u16*)(smem + 65536);   // [32 rows][16 units]
  u16* shFC = (u16*)smem;             // 8 rows x 1024 bf16 (post-loop only)

  const int tid = threadIdx.x;
  const int lane = tid & 63;
  const int wv = tid >> 6;           // K-quarter owner
  const int blk = blockIdx.x;
  const int mt8 = blk >> 6;          // group 0..7 = 32 batch rows
  const int ut = blk & 63;           // unit column (16 units x 4 gates)
  const int mt4 = mt8 >> 1;          // frag-layout batch tile
  const int mib = (mt8 & 1) * 2;     // mi base within mt4 (2 sub-tiles)

  const int mloc = lane & 15;
  const int q = lane >> 4;
  const int uglob = ut * 16 + mloc;

  unsigned* gflags = p.flags + mt8 * 256;   // 64 slots, stride 4 u32 (16B)

  float bias[4];
#pragma unroll
  for (int g = 0; g < 4; ++g) bias[g] = p.bi[g][uglob] + p.bh[g][uglob];

  float creg[2] = {0.f, 0.f};   // cell state for rows mt8*32 + wv*8 + q*2 + r

  // ---- h-weights resident in registers (128 VGPRs); x-weights streamed ----
  v8bf bhh[QH][4];
#pragma unroll
  for (int g = 0; g < 4; ++g)
#pragma unroll
    for (int i = 0; i < QH; ++i)
      bhh[i][g] = *((const v8bf*)p.wht[g] + ((size_t)(ut * KSH + wv * QH + i) * 64 + lane));

  for (int t = 0; t < kT; ++t) {
    v4f acc[2][4];    // [mi_loc][gate] partials for this wave's K-quarter
#pragma unroll
    for (int m = 0; m < 2; ++m)
#pragma unroll
      for (int g = 0; g < 4; ++g) acc[m][g] = (v4f){0.f, 0.f, 0.f, 0.f};

    // ---- phase X: x-part MFMAs, pre-poll (independent of h); wi from L2 ----
    const v8bf* xf = (const v8bf*)p.xt + ((size_t)(t * 4 + mt4) * 4 * KSX) * 64;
#pragma unroll
    for (int i = 0; i < QX; ++i) {
      v8bf bxl[4];
#pragma unroll
      for (int g = 0; g < 4; ++g)
        bxl[g] = *((const v8bf*)p.wit[g] + ((size_t)(ut * KSX + wv * QX + i) * 64 + lane));
#pragma unroll
      for (int ml = 0; ml < 2; ++ml) {
        const v8bf a = xf[(size_t)((mib + ml) * KSX + wv * QX + i) * 64 + lane];
#pragma unroll
        for (int g = 0; g < 4; ++g)
          acc[ml][g] = __builtin_amdgcn_mfma_f32_16x16x32_bf16(a, bxl[g], acc[ml][g], 0, 0, 0);
      }
    }

    if (t > 0) {
      if (wv == 0) {   // centralized poll (r5-best): 64 lanes x 64 flags
        while (true) {
          unsigned v = __hip_atomic_load(&gflags[lane * 4], __ATOMIC_RELAXED,
                                         __HIP_MEMORY_SCOPE_AGENT);
          if (__ballot(v >= (unsigned)t) == ~0ull) break;
          __builtin_amdgcn_s_sleep(1);
        }
      }
      __syncthreads();   // release all waves; also drains each wave's vmcnt
                         // so the counted waits below see exactly our issues

      // ---- phase H: per-wave private staging (r4 lesson), counted-vmcnt
      // overlap (r3-proven): compute mi0 while mi1 streams.
      const char* hread = (const char*)(p.hbuf + (size_t)(t & 1) * kB * kH);
      char* myHs = smem + wv * 16384;

#define STAGE_ML(ML)                                                          \
  _Pragma("unroll")                                                           \
  for (int i = 0; i < QH; ++i) {                                              \
    const size_t sl = (size_t)((mt4 * 4 + mib + (ML)) * KSH + wv * QH + i);   \
    ld16c(hread + sl * 1024 + lane * 16, myHs + ((ML) * QH + i) * 1024);      \
  }
#define COMPUTE_ML(ML)                                                        \
  _Pragma("unroll")                                                           \
  for (int i = 0; i < QH; ++i) {                                              \
    const v8bf a = *(const v8bf*)(myHs + ((ML) * QH + i) * 1024 + lane * 16); \
    _Pragma("unroll")                                                         \
    for (int g = 0; g < 4; ++g)                                               \
      acc[(ML)][g] = __builtin_amdgcn_mfma_f32_16x16x32_bf16(                 \
          a, bhh[i][g], acc[(ML)][g], 0, 0, 0);                               \
  }

      STAGE_ML(0) STAGE_ML(1)
      asm volatile("s_waitcnt vmcnt(8)" ::: "memory");
      __builtin_amdgcn_sched_barrier(0);
      COMPUTE_ML(0)
      asm volatile("s_waitcnt vmcnt(0)" ::: "memory");
      __builtin_amdgcn_sched_barrier(0);
      COMPUTE_ML(1)
#undef STAGE_ML
#undef COMPUTE_ML
    }

    __syncthreads();   // all phase-H ds_reads done: Red overlay now safe

    // ---- cross-wave K-reduction through LDS ----
#pragma unroll
    for (int ml = 0; ml < 2; ++ml)
#pragma unroll
      for (int g = 0; g < 4; ++g)
        Red[(wv * 8 + ml * 4 + g) * 64 + lane] = acc[ml][g];
    __syncthreads();

    // combine + gates: this thread owns rows mt8*32 + wv*8 + q*2 + {0,1},
    // unit uglob. C-frag element: row16 = q'*4 + reg, col = lane&15.
#pragma unroll
    for (int r = 0; r < 2; ++r) {
      const int lrow = wv * 8 + q * 2 + r;
      const int ml = lrow >> 4;
      const int r16 = lrow & 15;
      const int qp = r16 >> 2;
      const int reg = r16 & 3;
      float gacc[4];
#pragma unroll
      for (int g = 0; g < 4; ++g) {
        float s = 0.f;
#pragma unroll
        for (int kq = 0; kq < 4; ++kq)
          s += Redf[((kq * 8 + ml * 4 + g) * 64 + qp * 16 + mloc) * 4 + reg];
        gacc[g] = s;
      }
      const float iv = sigm(gacc[0] + bias[0]);
      const float fv = sigm(gacc[1] + bias[1]);
      const float gv = tanh_f(gacc[2] + bias[2]);
      const float ov = sigm(gacc[3] + bias[3]);
      creg[r] = fv * creg[r] + iv * gv;
      const float hv = ov * tanh_f(creg[r]);
      Hout[lrow * 16 + mloc] = f2b(hv);
    }
    __syncthreads();   // Hout complete

    // coalesced write-through: this block's h = 4 contiguous 256B runs
    // (mi_loc 0..1) x (hbit 0..1); 128 threads x 8B.
    if (tid < 128) {
      u16* hw = p.hbuf + (size_t)((t + 1) & 1) * kB * kH;
      const int run = tid >> 5;        // 0..3
      const int ml = run >> 1;
      const int hbit = run & 1;
      const int idx = tid & 31;
      const int row16 = idx >> 1;
      const int j0 = (idx & 1) * 4;
      const int hi = (ut & 1) * 2 + hbit;
      const u64 v = *(const u64*)&Hout[(ml * 16 + row16) * 16 + hbit * 8 + j0];
      u64* dst = (u64*)((char*)hw +
                        ((size_t)((mt4 * 4 + mib + ml) * KSH + (ut >> 1)) * 1024) +
                        hi * 256 + row16 * 16 + j0 * 2);
      __hip_atomic_store(dst, v, __ATOMIC_RELAXED, __HIP_MEMORY_SCOPE_AGENT);
    }

    __syncthreads();   // drains vmcnt: all h stores acked at LLC (r4-validated)
    if (tid == 0)      // publish IMMEDIATELY (r7 lesson)
      __hip_atomic_fetch_add(&gflags[ut * 4], 1u, __ATOMIC_RELAXED,
                             __HIP_MEMORY_SCOPE_AGENT);
  }

  // ---- FC + log_softmax: blocks 0..31, 8 rows x 32 cols. h_last in buf 0 ----
  if (blk < 32) {
    const int gg8 = blk >> 2;   // mt8 group of rows blk*8..+8
    if (wv == 0) {   // FC needs the WHOLE h -> centralized 64-flag poll (once)
      while (true) {
        unsigned v = __hip_atomic_load(&p.flags[gg8 * 256 + lane * 4], __ATOMIC_RELAXED,
                                       __HIP_MEMORY_SCOPE_AGENT);
        if (__ballot(v >= (unsigned)kT) == ~0ull) break;
        __builtin_amdgcn_s_sleep(1);
      }
    }
    __syncthreads();
    // stage 8 rows from frag-layout h into shFC[row][u] (small, once)
    {
      const int gg4 = blk >> 3;        // mt4 for frag indexing
      const int mi = (blk >> 1) & 3;
      const int ks2 = tid >> 3;        // 0..31
      const int ug = (tid >> 1) & 3;   // unit 8-group
      const int rh = tid & 1;          // row half
      u64* hf = (u64*)p.hbuf;          // buffer 0 (kT even)
#pragma unroll
      for (int rr = 0; rr < 4; ++rr) {
        const int row_l = rh * 4 + rr;
        const int r16 = (blk & 1) * 8 + row_l;
        const int L = r16 | (ug << 4);
        const size_t fi = ((size_t)((gg4 * 4 + mi) * KSH + ks2) * 64 + L) * 2;
        const u64 a = __hip_atomic_load(hf + fi, __ATOMIC_RELAXED, __HIP_MEMORY_SCOPE_AGENT);
        const u64 b = __hip_atomic_load(hf + fi + 1, __ATOMIC_RELAXED, __HIP_MEMORY_SCOPE_AGENT);
        u64* d = (u64*)&shFC[row_l * kH + ks2 * 32 + ug * 8];
        d[0] = a; d[1] = b;
      }
    }
    __syncthreads();
    const int row = tid >> 5;
    const int col = tid & 31;
    const u16* hr = &shFC[row * kH];
    const float* wr = p.wfc + (size_t)col * kH;
    float s = 0.f;
    for (int k = 0; k < kH; k += 4) {
      const float4 w4 = *(const float4*)(wr + k);
      s += b2f(hr[k]) * w4.x + b2f(hr[k + 1]) * w4.y +
           b2f(hr[k + 2]) * w4.z + b2f(hr[k + 3]) * w4.w;
    }
    float mx = s;
#pragma unroll
    for (int off = 16; off; off >>= 1) mx = fmaxf(mx, __shfl_xor(mx, off, 32));
    const float ex = __expf(s - mx);
    float se = ex;
#pragma unroll
    for (int off = 16; off; off >>= 1) se += __shfl_xor(se, off, 32);
    p.out[(blk * 8 + row) * kO + col] = s - mx - __logf(se);
  }
}

extern "C" void kernel_launch(void* const* d_in, const int* in_sizes, int n_in,
                              void* d_out, int out_size, void* d_ws, size_t ws_size,
                              hipStream_t stream) {
  (void)in_sizes; (void)n_in; (void)out_size; (void)ws_size;
  char* ws = (char*)d_ws;

  u16* xt = (u16*)(ws + OFF_XT);
  u16 *wit[4], *wht[4];
  for (int g = 0; g < 4; ++g) {
    wit[g] = (u16*)(ws + OFF_WIT + (size_t)g * SZ_WIT);
    wht[g] = (u16*)(ws + OFF_WHT + (size_t)g * SZ_WHT);
  }

  // dict order: x, (w_ii,w_hi,b_ii,b_hi), (w_if,w_hf,b_if,b_hf),
  //             (w_io,w_ho,b_io,b_ho), (w_ic,w_hc,b_ic,b_hc), w_fc
  // gate order: 0=i, 1=f, 2=g(candidate), 3=o
  const int gsrc[4] = {1, 5, 13, 9};

  // r10: fused prepass — one launch replaces memset + cvt_x + 8 cvt_w.
  PrepassParams pp;
  pp.x = (const float*)d_in[0];
  pp.xt = xt;
  for (int g = 0; g < 4; ++g) {
    pp.wi[g] = (const float*)d_in[gsrc[g]];
    pp.wh[g] = (const float*)d_in[gsrc[g] + 1];
    pp.wit[g] = wit[g];
    pp.wht[g] = wht[g];
  }
  pp.flags = (unsigned*)(ws + OFF_FLG);
  prepass<<<dim3(8192 + 4 * 256 + 4 * 512 + 1), dim3(256), 0, stream>>>(pp);

  LstmParams p;
  p.xt = xt;
  for (int g = 0; g < 4; ++g) {
    p.wit[g] = wit[g];
    p.wht[g] = wht[g];
    p.bi[g] = (const float*)d_in[gsrc[g] + 2];
    p.bh[g] = (const float*)d_in[gsrc[g] + 3];
  }
  p.wfc = (const float*)d_in[17];
  p.out = (float*)d_out;
  p.flags = (unsigned*)(ws + OFF_FLG);
  p.hbuf = (u16*)(ws + OFF_H);

  void* args[] = {&p};
  hipError_t e = hipLaunchCooperativeKernel((void*)lstm_kernel, dim3(kBlocks),
                                            dim3(kThreads), args, 0, stream);
  if (e != hipSuccess) {
    // Never fail silently (r5 lesson). __launch_bounds__(256,2) + 66.5 KB LDS
    // guarantee 2 blocks/CU -> all 512 blocks co-resident on 256 CUs; the
    // group-contiguous mapping additionally makes partial residency safe.
    (void)hipGetLastError();   // clear sticky error
    lstm_kernel<<<dim3(kBlocks), dim3(kThreads), 0, stream>>>(p);
  }
}